// Round 19
// baseline (156.951 us; speedup 1.0000x reference)
//
#include <hip/hip_runtime.h>
#include <math.h>

typedef unsigned int   u32;
typedef unsigned long long u64;

#define BATCH   8
#define NDATA   8192
#define NPOINT  1024
#define NSAMPLE 32
#define CFEAT   64
#define ROWF    67            // 3 xyz + 64 feat
#define MAXCAND 128           // in-radius count per query is ~6-60; 128 is ample
#define QPB     4             // queries per block = waves per block
#define NB      256           // x-buckets per batch

// f32-element offsets of the concatenated outputs
#define OUT_IDX (BATCH*NPOINT*NSAMPLE*ROWF)              // 17563648
#define OUT_GX  (OUT_IDX + BATCH*NPOINT*NSAMPLE)         // 17825792

// f32 -> bf16 (RNE) -> f32: match the harness's bf16-rounded np reference
__device__ __forceinline__ float rnbf(float f) {
    u32 b = __float_as_uint(f);
    b += 0x7FFFu + ((b >> 16) & 1u);
    return __uint_as_float(b & 0xFFFF0000u);
}
__device__ __forceinline__ int clampidx(int v) {
    return (v < 0) ? 0 : (v > NDATA-1 ? NDATA-1 : v);
}
// monotone x->bucket map, shared by binning and query (covering by monotonicity)
__device__ __forceinline__ int xbucket(float v) {
    int c = (int)floorf((v + 4.5f) * 28.444445f);   // 256 buckets over [-4.5, 4.5]
    return c < 0 ? 0 : (c > NB-1 ? NB-1 : c);
}

// ---- K1: per-batch bucket sort by x -> interleaved float4 {x,y,z,idbits} ----
__global__ __launch_bounds__(1024)
void bin_kernel(const float* __restrict__ xyz,
                float4* __restrict__ wp, u32* __restrict__ wst)
{
    __shared__ u32 cnt[NB];    // counts -> cursors
    __shared__ u32 sc[NB];     // scan buffer
    const int b = blockIdx.x, tid = threadIdx.x;   // 1024 threads
    const float* bx = xyz + (size_t)b * NDATA * 3;

    if (tid < NB) cnt[tid] = 0;
    __syncthreads();
    for (int p = tid; p < NDATA; p += 1024)
        atomicAdd(&cnt[xbucket(bx[p*3])], 1u);
    __syncthreads();

    // parallel inclusive scan (Hillis-Steele, 8 steps, block-uniform barriers)
    if (tid < NB) sc[tid] = cnt[tid];
    __syncthreads();
    #pragma unroll
    for (int d = 1; d < NB; d <<= 1) {
        u32 t = 0;
        if (tid < NB && tid >= d) t = sc[tid - d];
        __syncthreads();
        if (tid < NB && tid >= d) sc[tid] += t;
        __syncthreads();
    }
    if (tid < NB) {
        u32 excl = (tid == 0) ? 0u : sc[tid - 1];
        cnt[tid] = excl;                           // cursor
        wst[b*(NB+1) + tid] = excl;
        if (tid == 0) wst[b*(NB+1) + NB] = NDATA;
    }
    __syncthreads();

    for (int p = tid; p < NDATA; p += 1024) {      // scatter (bucket order arbitrary)
        float x = bx[p*3], y = bx[p*3+1], z = bx[p*3+2];
        u32 pos = atomicAdd(&cnt[xbucket(x)], 1u);
        wp[(size_t)b*NDATA + pos] = make_float4(x, y, z, __uint_as_float((u32)p));
    }
}

// ---- K2: windowed scan + verified selection/epilogue ----
__global__ __launch_bounds__(256, 8)
void grouping_kernel(const float* __restrict__ new_xyz,
                     const float* __restrict__ xyz,
                     const float* __restrict__ points,
                     const float4* __restrict__ wp, const u32* __restrict__ wst,
                     float* __restrict__ out, float T)
{
    __shared__ float cand_s[QPB][MAXCAND];   // f32 sqrt(d2)
    __shared__ int   cand_i[QPB][MAXCAND];   // point index (tie-break key)
    __shared__ int   sel[QPB][NSAMPLE];

    const int tid  = threadIdx.x;
    const int wv   = tid >> 6;
    const int lane = tid & 63;
    const int q    = blockIdx.x * QPB + wv;   // one query per wave
    const int b    = q >> 10;                 // batch

    if (lane < NSAMPLE) sel[wv][lane] = 0;    // safety net; overwritten below

    const float qx = new_xyz[q*3 + 0];
    const float qy = new_xyz[q*3 + 1];
    const float qz = new_xyz[q*3 + 2];
    const float*  bx = xyz + (size_t)b * NDATA * 3;
    const float4* cp = wp  + (size_t)b * NDATA;

    // x-window (margin 0.2005 >> any f32 rounding slop in the d2<T chain)
    const int blo = xbucket(__fsub_rn(qx, 0.2005f));
    const int bhi = xbucket(__fadd_rn(qx, 0.2005f));
    const u32 j0 = wst[b*(NB+1) + blo];
    const u32 j1 = wst[b*(NB+1) + bhi + 1];

    int n = 0;                                // wave-uniform candidate count
    for (u32 jb = j0; jb < j1; jb += 64) {    // coalesced float4 reads
        u32 j  = jb + lane;
        bool in = j < j1;
        u32 jj = in ? j : (j1 - 1);           // safe clamp (j1 >= 1 inside loop)
        float4 v = cp[jj];
        // exact np f32 semantics: no FMA, left-to-right sum
        float dx = __fsub_rn(v.x, qx);
        float dy = __fsub_rn(v.y, qy);
        float dz = __fsub_rn(v.z, qz);
        float d2 = __fadd_rn(__fadd_rn(__fmul_rn(dx,dx), __fmul_rn(dy,dy)),
                             __fmul_rn(dz,dz));
        bool cc = in && (d2 < T);             // == sqrtf(d2) < 0.2f (monotone)
        u64 m = __ballot(cc);
        if (m) {
            if (cc) {
                int below = __builtin_amdgcn_mbcnt_hi((u32)(m >> 32),
                             __builtin_amdgcn_mbcnt_lo((u32)m, 0));
                int pos = n + below;
                if (pos < MAXCAND) {
                    cand_s[wv][pos] = __fsqrt_rn(d2);   // ref sorts the f32 norm
                    cand_i[wv][pos] = (int)__float_as_uint(v.w);
                }
            }
            n += (int)__popcll(m);
        }
    }

    // ---- rare pass: argmin for empty-ball queries (coalesced binned reads;
    //      same float values as AoS => identical d2/sqrt; (sqrt, lowest-id)
    //      lex reduction is order-independent => same result as index-order) ----
    int mini = 0;
    if (n == 0) {
        float ms = 3.402823466e38f; int mi = 0x7FFFFFFF;
        for (int k = 0; k < NDATA/64; ++k) {
            float4 v = cp[(k << 6) + lane];
            float dx = __fsub_rn(v.x, qx);
            float dy = __fsub_rn(v.y, qy);
            float dz = __fsub_rn(v.z, qz);
            float d2 = __fadd_rn(__fadd_rn(__fmul_rn(dx,dx), __fmul_rn(dy,dy)),
                                 __fmul_rn(dz,dz));
            float s  = __fsqrt_rn(d2);                // np tie rule on sqrt values
            int   id = (int)__float_as_uint(v.w);
            if (s < ms || (s == ms && id < mi)) { ms = s; mi = id; }
        }
        for (int off = 32; off; off >>= 1) {
            float os = __shfl_xor(ms, off);
            int   oi = __shfl_xor(mi, off);
            if (os < ms || (os == ms && oi < mi)) { ms = os; mi = oi; }
        }
        mini = mi;
    }

    __syncthreads();   // block-uniform (loops above have no barriers)

    // ---- rank-place: (dist, point-index) lex == np stable argsort ----
    const int nj = n > MAXCAND ? MAXCAND : n;
    for (int kk = lane; kk < nj; kk += 64) {
        float sk = cand_s[wv][kk];
        int   ik = cand_i[wv][kk];
        int r = 0;
        for (int mm = 0; mm < nj; ++mm) {           // broadcast LDS reads
            float sm = cand_s[wv][mm];
            int   im = cand_i[wv][mm];
            r += (int)((sm < sk) | ((sm == sk) & (im < ik)));
        }
        if (r < NSAMPLE) sel[wv][r] = clampidx(ik);
    }
    __syncthreads();
    {
        const int nsel = nj < NSAMPLE ? nj : NSAMPLE;
        if (lane >= nsel && lane < NSAMPLE) {
            int pad = (nj > 0) ? sel[wv][0] : clampidx(mini);   // sorted_idx[0]
            sel[wv][lane] = pad;
        }
    }
    __syncthreads();

    // ---- outputs: f32 stores, values pre-rounded through bf16 ----
    // idx (chunk 1)
    if (lane < NSAMPLE)
        out[OUT_IDX + (size_t)q*NSAMPLE + lane] = rnbf((float)sel[wv][lane]);

    // grouped_xyz (chunk 2)
    for (int e = lane; e < NSAMPLE*3; e += 64) {
        int sR = e / 3, c2 = e - sR*3;
        int is = sel[wv][sR];
        out[OUT_GX + (size_t)q*(NSAMPLE*3) + e] = rnbf(bx[is*3 + c2]);
    }

    // new_points (chunk 0): float4 row-major pass (base q*2144 dwords: 16B-aligned)
    const float* prow = points + (size_t)b * NDATA * CFEAT;
    float4* onp4 = (float4*)(out + (size_t)q * (NSAMPLE*ROWF));
    for (int e4 = lane; e4 < (NSAMPLE*ROWF)/4; e4 += 64) {   // 536 per query
        int d0 = e4 << 2;
        float vals[4];
        #pragma unroll
        for (int j = 0; j < 4; ++j) {
            int d  = d0 + j;
            int sR = d / ROWF;
            int c2 = d - sR*ROWF;
            int is = sel[wv][sR];
            const float* ap = (c2 < 3) ? (bx + (size_t)is*3 + c2)
                                       : (prow + (size_t)is*CFEAT + (c2-3));
            vals[j] = rnbf(*ap);
        }
        onp4[e4] = make_float4(vals[0], vals[1], vals[2], vals[3]);
    }
}

extern "C" void kernel_launch(void* const* d_in, const int* in_sizes, int n_in,
                              void* d_out, int out_size, void* d_ws, size_t ws_size,
                              hipStream_t stream) {
    // T = smallest f32 x with sqrtf(x) >= 0.2f  =>  (d2 < T) == (sqrtf(d2) < 0.2f)
    union { u32 u; float f; } lo, hi, mid;
    lo.u = 0u; hi.f = 0.05f;
    while (hi.u - lo.u > 1u) {
        mid.u = lo.u + (hi.u - lo.u) / 2u;
        if (sqrtf(mid.f) >= 0.2f) hi.u = mid.u; else lo.u = mid.u;
    }
    float T = hi.f;

    // ws layout: wp (float4, 1 MB) | wst (u32 starts, ~8.2 KB)
    float4* wp  = (float4*)d_ws;
    u32*    wst = (u32*)(wp + (size_t)BATCH*NDATA);

    const float* nxz = (const float*)d_in[0];
    const float* xyz = (const float*)d_in[1];
    const float* pts = (const float*)d_in[2];

    bin_kernel<<<BATCH, 1024, 0, stream>>>(xyz, wp, wst);
    grouping_kernel<<<(BATCH*NPOINT)/QPB, 256, 0, stream>>>(
        nxz, xyz, pts, wp, wst, (float*)d_out, T);
}

// Round 20
// 153.733 us; speedup vs baseline: 1.0209x; 1.0209x over previous
//
#include <hip/hip_runtime.h>
#include <math.h>

typedef unsigned int   u32;
typedef unsigned long long u64;

#define BATCH   8
#define NDATA   8192
#define NPOINT  1024
#define NSAMPLE 32
#define CFEAT   64
#define ROWF    67            // 3 xyz + 64 feat
#define MAXCAND 128           // in-radius count per query is ~6-60; 128 is ample
#define QPB     4             // queries per block = waves per block
#define NB      256           // x-buckets per batch

// f32-element offsets of the concatenated outputs
#define OUT_IDX (BATCH*NPOINT*NSAMPLE*ROWF)              // 17563648
#define OUT_GX  (OUT_IDX + BATCH*NPOINT*NSAMPLE)         // 17825792

// f32 -> bf16 (RNE) -> f32: match the harness's bf16-rounded np reference
__device__ __forceinline__ float rnbf(float f) {
    u32 b = __float_as_uint(f);
    b += 0x7FFFu + ((b >> 16) & 1u);
    return __uint_as_float(b & 0xFFFF0000u);
}
__device__ __forceinline__ int clampidx(int v) {
    return (v < 0) ? 0 : (v > NDATA-1 ? NDATA-1 : v);
}
// monotone x->bucket map, shared by binning and query (covering by monotonicity)
__device__ __forceinline__ int xbucket(float v) {
    int c = (int)floorf((v + 4.5f) * 28.444445f);   // 256 buckets over [-4.5, 4.5]
    return c < 0 ? 0 : (c > NB-1 ? NB-1 : c);
}

// ---- K1: per-batch bucket sort by x -> interleaved float4 {x,y,z,idbits} ----
__global__ __launch_bounds__(1024)
void bin_kernel(const float* __restrict__ xyz,
                float4* __restrict__ wp, u32* __restrict__ wst)
{
    __shared__ u32 cnt[NB];    // counts -> cursors
    __shared__ u32 sc[NB];     // scan buffer
    const int b = blockIdx.x, tid = threadIdx.x;   // 1024 threads
    const float* bx = xyz + (size_t)b * NDATA * 3;

    if (tid < NB) cnt[tid] = 0;
    __syncthreads();
    for (int p = tid; p < NDATA; p += 1024)
        atomicAdd(&cnt[xbucket(bx[p*3])], 1u);
    __syncthreads();

    // parallel inclusive scan (Hillis-Steele, 8 steps, block-uniform barriers)
    if (tid < NB) sc[tid] = cnt[tid];
    __syncthreads();
    #pragma unroll
    for (int d = 1; d < NB; d <<= 1) {
        u32 t = 0;
        if (tid < NB && tid >= d) t = sc[tid - d];
        __syncthreads();
        if (tid < NB && tid >= d) sc[tid] += t;
        __syncthreads();
    }
    if (tid < NB) {
        u32 excl = (tid == 0) ? 0u : sc[tid - 1];
        cnt[tid] = excl;                           // cursor
        wst[b*(NB+1) + tid] = excl;
        if (tid == 0) wst[b*(NB+1) + NB] = NDATA;
    }
    __syncthreads();

    for (int p = tid; p < NDATA; p += 1024) {      // scatter (bucket order arbitrary)
        float x = bx[p*3], y = bx[p*3+1], z = bx[p*3+2];
        u32 pos = atomicAdd(&cnt[xbucket(x)], 1u);
        wp[(size_t)b*NDATA + pos] = make_float4(x, y, z, __uint_as_float((u32)p));
    }
}

// ---- K2: windowed scan + verified selection/epilogue ----
__global__ __launch_bounds__(256, 8)
void grouping_kernel(const float* __restrict__ new_xyz,
                     const float* __restrict__ xyz,
                     const float* __restrict__ points,
                     const float4* __restrict__ wp, const u32* __restrict__ wst,
                     float* __restrict__ out, float T)
{
    __shared__ float cand_s[QPB][MAXCAND];   // f32 sqrt(d2)
    __shared__ int   cand_i[QPB][MAXCAND];   // point index (tie-break key)
    __shared__ int   sel[QPB][NSAMPLE];

    const int tid  = threadIdx.x;
    const int wv   = tid >> 6;
    const int lane = tid & 63;
    const int q    = blockIdx.x * QPB + wv;   // one query per wave
    const int b    = q >> 10;                 // batch

    if (lane < NSAMPLE) sel[wv][lane] = 0;    // safety net; overwritten below

    const float qx = new_xyz[q*3 + 0];
    const float qy = new_xyz[q*3 + 1];
    const float qz = new_xyz[q*3 + 2];
    const float*  bx = xyz + (size_t)b * NDATA * 3;
    const float4* cp = wp  + (size_t)b * NDATA;

    // x-window (margin 0.2005 >> any f32 rounding slop in the d2<T chain)
    const int blo = xbucket(__fsub_rn(qx, 0.2005f));
    const int bhi = xbucket(__fadd_rn(qx, 0.2005f));
    const u32 j0 = wst[b*(NB+1) + blo];
    const u32 j1 = wst[b*(NB+1) + bhi + 1];

    int n = 0;                                // wave-uniform candidate count
    for (u32 jb = j0; jb < j1; jb += 64) {    // coalesced float4 reads
        u32 j  = jb + lane;
        bool in = j < j1;
        u32 jj = in ? j : (j1 - 1);           // safe clamp (j1 >= 1 inside loop)
        float4 v = cp[jj];
        // exact np f32 semantics: no FMA, left-to-right sum
        float dx = __fsub_rn(v.x, qx);
        float dy = __fsub_rn(v.y, qy);
        float dz = __fsub_rn(v.z, qz);
        float d2 = __fadd_rn(__fadd_rn(__fmul_rn(dx,dx), __fmul_rn(dy,dy)),
                             __fmul_rn(dz,dz));
        bool cc = in && (d2 < T);             // == sqrtf(d2) < 0.2f (monotone)
        u64 m = __ballot(cc);
        if (m) {
            if (cc) {
                int below = __builtin_amdgcn_mbcnt_hi((u32)(m >> 32),
                             __builtin_amdgcn_mbcnt_lo((u32)m, 0));
                int pos = n + below;
                if (pos < MAXCAND) {
                    cand_s[wv][pos] = __fsqrt_rn(d2);   // ref sorts the f32 norm
                    cand_i[wv][pos] = (int)__float_as_uint(v.w);
                }
            }
            n += (int)__popcll(m);
        }
    }

    // ---- rare pass: argmin for empty-ball queries (coalesced binned reads;
    //      same float values as AoS => identical d2/sqrt; (sqrt, lowest-id)
    //      lex reduction is order-independent => same result as index-order) ----
    int mini = 0;
    if (n == 0) {
        float ms = 3.402823466e38f; int mi = 0x7FFFFFFF;
        for (int k = 0; k < NDATA/64; ++k) {
            float4 v = cp[(k << 6) + lane];
            float dx = __fsub_rn(v.x, qx);
            float dy = __fsub_rn(v.y, qy);
            float dz = __fsub_rn(v.z, qz);
            float d2 = __fadd_rn(__fadd_rn(__fmul_rn(dx,dx), __fmul_rn(dy,dy)),
                                 __fmul_rn(dz,dz));
            float s  = __fsqrt_rn(d2);                // np tie rule on sqrt values
            int   id = (int)__float_as_uint(v.w);
            if (s < ms || (s == ms && id < mi)) { ms = s; mi = id; }
        }
        for (int off = 32; off; off >>= 1) {
            float os = __shfl_xor(ms, off);
            int   oi = __shfl_xor(mi, off);
            if (os < ms || (os == ms && oi < mi)) { ms = os; mi = oi; }
        }
        mini = mi;
    }

    __syncthreads();   // block-uniform (loops above have no barriers)

    // ---- rank-place: (dist, point-index) lex == np stable argsort ----
    const int nj = n > MAXCAND ? MAXCAND : n;
    for (int kk = lane; kk < nj; kk += 64) {
        float sk = cand_s[wv][kk];
        int   ik = cand_i[wv][kk];
        int r = 0;
        for (int mm = 0; mm < nj; ++mm) {           // broadcast LDS reads
            float sm = cand_s[wv][mm];
            int   im = cand_i[wv][mm];
            r += (int)((sm < sk) | ((sm == sk) & (im < ik)));
        }
        if (r < NSAMPLE) sel[wv][r] = clampidx(ik);
    }
    __syncthreads();
    {
        const int nsel = nj < NSAMPLE ? nj : NSAMPLE;
        if (lane >= nsel && lane < NSAMPLE) {
            int pad = (nj > 0) ? sel[wv][0] : clampidx(mini);   // sorted_idx[0]
            sel[wv][lane] = pad;
        }
    }
    __syncthreads();

    // ---- outputs: f32 stores, values pre-rounded through bf16 ----
    // idx (chunk 1)
    if (lane < NSAMPLE)
        out[OUT_IDX + (size_t)q*NSAMPLE + lane] = rnbf((float)sel[wv][lane]);

    // grouped_xyz (chunk 2)
    for (int e = lane; e < NSAMPLE*3; e += 64) {
        int sR = e / 3, c2 = e - sR*3;
        int is = sel[wv][sR];
        out[OUT_GX + (size_t)q*(NSAMPLE*3) + e] = rnbf(bx[is*3 + c2]);
    }

    // new_points (chunk 0): scalar row-major pass — one independent gather per
    // lane per iter (pipelineable), coalesced stores, each 64 B line written once
    const float* prow = points + (size_t)b * NDATA * CFEAT;
    float* onp = out + (size_t)q * (NSAMPLE*ROWF);
    for (int e = lane; e < NSAMPLE*ROWF; e += 64) {
        int sR = e / ROWF;
        int c2 = e - sR*ROWF;
        int is = sel[wv][sR];
        const float* ap = (c2 < 3) ? (bx + (size_t)is*3 + c2)
                                   : (prow + (size_t)is*CFEAT + (c2-3));
        onp[e] = rnbf(*ap);
    }
}

extern "C" void kernel_launch(void* const* d_in, const int* in_sizes, int n_in,
                              void* d_out, int out_size, void* d_ws, size_t ws_size,
                              hipStream_t stream) {
    // T = smallest f32 x with sqrtf(x) >= 0.2f  =>  (d2 < T) == (sqrtf(d2) < 0.2f)
    union { u32 u; float f; } lo, hi, mid;
    lo.u = 0u; hi.f = 0.05f;
    while (hi.u - lo.u > 1u) {
        mid.u = lo.u + (hi.u - lo.u) / 2u;
        if (sqrtf(mid.f) >= 0.2f) hi.u = mid.u; else lo.u = mid.u;
    }
    float T = hi.f;

    // ws layout: wp (float4, 1 MB) | wst (u32 starts, ~8.2 KB)
    float4* wp  = (float4*)d_ws;
    u32*    wst = (u32*)(wp + (size_t)BATCH*NDATA);

    const float* nxz = (const float*)d_in[0];
    const float* xyz = (const float*)d_in[1];
    const float* pts = (const float*)d_in[2];

    bin_kernel<<<BATCH, 1024, 0, stream>>>(xyz, wp, wst);
    grouping_kernel<<<(BATCH*NPOINT)/QPB, 256, 0, stream>>>(
        nxz, xyz, pts, wp, wst, (float*)d_out, T);
}

// Round 21
// 138.404 us; speedup vs baseline: 1.1340x; 1.1108x over previous
//
#include <hip/hip_runtime.h>
#include <math.h>

typedef unsigned int   u32;
typedef unsigned long long u64;

#define BATCH   8
#define NDATA   8192
#define NPOINT  1024
#define NSAMPLE 32
#define CFEAT   64
#define ROWF    67            // 3 xyz + 64 feat
#define MAXCAND 128           // in-radius count per query is ~6-60; 128 is ample
#define QPB     4             // queries per block = waves per block
#define NB      256           // x-buckets per batch

// f32-element offsets of the concatenated outputs
#define OUT_IDX (BATCH*NPOINT*NSAMPLE*ROWF)              // 17563648
#define OUT_GX  (OUT_IDX + BATCH*NPOINT*NSAMPLE)         // 17825792

// f32 -> bf16 (RNE) -> f32: match the harness's bf16-rounded np reference
__device__ __forceinline__ float rnbf(float f) {
    u32 b = __float_as_uint(f);
    b += 0x7FFFu + ((b >> 16) & 1u);
    return __uint_as_float(b & 0xFFFF0000u);
}
__device__ __forceinline__ int clampidx(int v) {
    return (v < 0) ? 0 : (v > NDATA-1 ? NDATA-1 : v);
}
// monotone x->bucket map, shared by binning and query (covering by monotonicity)
__device__ __forceinline__ int xbucket(float v) {
    int c = (int)floorf((v + 4.5f) * 28.444445f);   // 256 buckets over [-4.5, 4.5]
    return c < 0 ? 0 : (c > NB-1 ? NB-1 : c);
}

// ---- K1: per-batch bucket sort by x -> interleaved float4 {x,y,z,idbits} ----
__global__ __launch_bounds__(1024)
void bin_kernel(const float* __restrict__ xyz,
                float4* __restrict__ wp, u32* __restrict__ wst)
{
    __shared__ u32 cnt[NB];    // counts -> cursors
    __shared__ u32 sc[NB];     // scan buffer
    const int b = blockIdx.x, tid = threadIdx.x;   // 1024 threads
    const float* bx = xyz + (size_t)b * NDATA * 3;

    if (tid < NB) cnt[tid] = 0;
    __syncthreads();
    for (int p = tid; p < NDATA; p += 1024)
        atomicAdd(&cnt[xbucket(bx[p*3])], 1u);
    __syncthreads();

    // parallel inclusive scan (Hillis-Steele, 8 steps, block-uniform barriers)
    if (tid < NB) sc[tid] = cnt[tid];
    __syncthreads();
    #pragma unroll
    for (int d = 1; d < NB; d <<= 1) {
        u32 t = 0;
        if (tid < NB && tid >= d) t = sc[tid - d];
        __syncthreads();
        if (tid < NB && tid >= d) sc[tid] += t;
        __syncthreads();
    }
    if (tid < NB) {
        u32 excl = (tid == 0) ? 0u : sc[tid - 1];
        cnt[tid] = excl;                           // cursor
        wst[b*(NB+1) + tid] = excl;
        if (tid == 0) wst[b*(NB+1) + NB] = NDATA;
    }
    __syncthreads();

    for (int p = tid; p < NDATA; p += 1024) {      // scatter (bucket order arbitrary)
        float x = bx[p*3], y = bx[p*3+1], z = bx[p*3+2];
        u32 pos = atomicAdd(&cnt[xbucket(x)], 1u);
        wp[(size_t)b*NDATA + pos] = make_float4(x, y, z, __uint_as_float((u32)p));
    }
}

// ---- K2: windowed scan + selection; writes idx, grouped_xyz, sel->ws ----
__global__ __launch_bounds__(256, 8)
void grouping_kernel(const float* __restrict__ new_xyz,
                     const float* __restrict__ xyz,
                     const float* __restrict__ points,
                     const float4* __restrict__ wp, const u32* __restrict__ wst,
                     u32* __restrict__ selws,
                     float* __restrict__ out, float T)
{
    __shared__ float cand_s[QPB][MAXCAND];   // f32 sqrt(d2)
    __shared__ int   cand_i[QPB][MAXCAND];   // point index (tie-break key)
    __shared__ int   sel[QPB][NSAMPLE];

    const int tid  = threadIdx.x;
    const int wv   = tid >> 6;
    const int lane = tid & 63;
    const int q    = blockIdx.x * QPB + wv;   // one query per wave
    const int b    = q >> 10;                 // batch

    if (lane < NSAMPLE) sel[wv][lane] = 0;    // safety net; overwritten below

    const float qx = new_xyz[q*3 + 0];
    const float qy = new_xyz[q*3 + 1];
    const float qz = new_xyz[q*3 + 2];
    const float*  bx = xyz + (size_t)b * NDATA * 3;
    const float4* cp = wp  + (size_t)b * NDATA;

    // x-window (margin 0.2005 >> any f32 rounding slop in the d2<T chain)
    const int blo = xbucket(__fsub_rn(qx, 0.2005f));
    const int bhi = xbucket(__fadd_rn(qx, 0.2005f));
    const u32 j0 = wst[b*(NB+1) + blo];
    const u32 j1 = wst[b*(NB+1) + bhi + 1];

    int n = 0;                                // wave-uniform candidate count
    for (u32 jb = j0; jb < j1; jb += 64) {    // coalesced float4 reads
        u32 j  = jb + lane;
        bool in = j < j1;
        u32 jj = in ? j : (j1 - 1);           // safe clamp (j1 >= 1 inside loop)
        float4 v = cp[jj];
        // exact np f32 semantics: no FMA, left-to-right sum
        float dx = __fsub_rn(v.x, qx);
        float dy = __fsub_rn(v.y, qy);
        float dz = __fsub_rn(v.z, qz);
        float d2 = __fadd_rn(__fadd_rn(__fmul_rn(dx,dx), __fmul_rn(dy,dy)),
                             __fmul_rn(dz,dz));
        bool cc = in && (d2 < T);             // == sqrtf(d2) < 0.2f (monotone)
        u64 m = __ballot(cc);
        if (m) {
            if (cc) {
                int below = __builtin_amdgcn_mbcnt_hi((u32)(m >> 32),
                             __builtin_amdgcn_mbcnt_lo((u32)m, 0));
                int pos = n + below;
                if (pos < MAXCAND) {
                    cand_s[wv][pos] = __fsqrt_rn(d2);   // ref sorts the f32 norm
                    cand_i[wv][pos] = (int)__float_as_uint(v.w);
                }
            }
            n += (int)__popcll(m);
        }
    }

    // ---- rare pass: argmin for empty-ball queries (R18-verified form) ----
    int mini = 0;
    if (n == 0) {
        float mind = 3.402823466e38f; int mi = 0;
        for (int k = 0; k < NDATA/64; ++k) {
            int i = (k << 6) + lane;
            float dx = __fsub_rn(bx[i*3+0], qx);
            float dy = __fsub_rn(bx[i*3+1], qy);
            float dz = __fsub_rn(bx[i*3+2], qz);
            float d2 = __fadd_rn(__fadd_rn(__fmul_rn(dx,dx), __fmul_rn(dy,dy)),
                                 __fmul_rn(dz,dz));
            if (d2 < mind) { mind = d2; mi = i; }   // strict <: lowest idx per lane
        }
        float ms = __fsqrt_rn(mind);                // np tie rule on sqrt values
        for (int off = 32; off; off >>= 1) {
            float os = __shfl_xor(ms, off);
            int   oi = __shfl_xor(mi, off);
            if (os < ms || (os == ms && oi < mi)) { ms = os; mi = oi; }
        }
        mini = mi;
    }

    __syncthreads();   // block-uniform (loops above have no barriers)

    // ---- rank-place: (dist, point-index) lex == np stable argsort ----
    const int nj = n > MAXCAND ? MAXCAND : n;
    for (int kk = lane; kk < nj; kk += 64) {
        float sk = cand_s[wv][kk];
        int   ik = cand_i[wv][kk];
        int r = 0;
        for (int mm = 0; mm < nj; ++mm) {           // broadcast LDS reads
            float sm = cand_s[wv][mm];
            int   im = cand_i[wv][mm];
            r += (int)((sm < sk) | ((sm == sk) & (im < ik)));
        }
        if (r < NSAMPLE) sel[wv][r] = clampidx(ik);
    }
    __syncthreads();
    {
        const int nsel = nj < NSAMPLE ? nj : NSAMPLE;
        if (lane >= nsel && lane < NSAMPLE) {
            int pad = (nj > 0) ? sel[wv][0] : clampidx(mini);   // sorted_idx[0]
            sel[wv][lane] = pad;
        }
    }
    __syncthreads();

    // ---- outputs: idx (chunk 1), grouped_xyz (chunk 2), sel -> workspace ----
    if (lane < NSAMPLE) {
        int v = sel[wv][lane];
        out[OUT_IDX + (size_t)q*NSAMPLE + lane] = rnbf((float)v);
        selws[(size_t)q*NSAMPLE + lane] = (u32)v;
    }
    for (int e = lane; e < NSAMPLE*3; e += 64) {
        int sR = e / 3, c2 = e - sR*3;
        int is = sel[wv][sR];
        out[OUT_GX + (size_t)q*(NSAMPLE*3) + e] = rnbf(bx[is*3 + c2]);
    }
}

// ---- K3: new_points gather (one query per block, full-machine occupancy) ----
__global__ __launch_bounds__(256, 8)
void gather_kernel(const float* __restrict__ xyz,
                   const float* __restrict__ points,
                   const u32* __restrict__ selws,
                   float* __restrict__ out)
{
    __shared__ int ssel[NSAMPLE];
    const int q = blockIdx.x;                 // 8192 blocks
    const int b = q >> 10;
    if (threadIdx.x < NSAMPLE)
        ssel[threadIdx.x] = (int)selws[(size_t)q*NSAMPLE + threadIdx.x];
    __syncthreads();

    const float* bx   = xyz    + (size_t)b * NDATA * 3;
    const float* prow = points + (size_t)b * NDATA * CFEAT;
    float* onp = out + (size_t)q * (NSAMPLE*ROWF);
    for (int e = threadIdx.x; e < NSAMPLE*ROWF; e += 256) {
        int sR = e / ROWF;
        int c2 = e - sR*ROWF;
        int is = ssel[sR];
        const float* ap = (c2 < 3) ? (bx + (size_t)is*3 + c2)
                                   : (prow + (size_t)is*CFEAT + (c2-3));
        onp[e] = rnbf(*ap);
    }
}

extern "C" void kernel_launch(void* const* d_in, const int* in_sizes, int n_in,
                              void* d_out, int out_size, void* d_ws, size_t ws_size,
                              hipStream_t stream) {
    // T = smallest f32 x with sqrtf(x) >= 0.2f  =>  (d2 < T) == (sqrtf(d2) < 0.2f)
    union { u32 u; float f; } lo, hi, mid;
    lo.u = 0u; hi.f = 0.05f;
    while (hi.u - lo.u > 1u) {
        mid.u = lo.u + (hi.u - lo.u) / 2u;
        if (sqrtf(mid.f) >= 0.2f) hi.u = mid.u; else lo.u = mid.u;
    }
    float T = hi.f;

    // ws layout: wp (float4, 1 MB) | wst (~8.2 KB) | selws (1 MB)
    float4* wp  = (float4*)d_ws;
    u32*    wst = (u32*)(wp + (size_t)BATCH*NDATA);
    u32*    selws = wst + BATCH*(NB+1);

    const float* nxz = (const float*)d_in[0];
    const float* xyz = (const float*)d_in[1];
    const float* pts = (const float*)d_in[2];

    bin_kernel<<<BATCH, 1024, 0, stream>>>(xyz, wp, wst);
    grouping_kernel<<<(BATCH*NPOINT)/QPB, 256, 0, stream>>>(
        nxz, xyz, pts, wp, wst, selws, (float*)d_out, T);
    gather_kernel<<<BATCH*NPOINT, 256, 0, stream>>>(xyz, pts, selws, (float*)d_out);
}

// Round 22
// 129.604 us; speedup vs baseline: 1.2110x; 1.0679x over previous
//
#include <hip/hip_runtime.h>
#include <math.h>

typedef unsigned int   u32;
typedef unsigned long long u64;

#define BATCH   8
#define NDATA   8192
#define NPOINT  1024
#define NSAMPLE 32
#define CFEAT   64
#define ROWF    67            // 3 xyz + 64 feat
#define MAXCAND 128           // in-radius count per query is ~6-60; 128 is ample
#define QPB     4             // queries per block = waves per block
#define NB      256           // x-buckets per batch

// f32-element offsets of the concatenated outputs
#define OUT_IDX (BATCH*NPOINT*NSAMPLE*ROWF)              // 17563648
#define OUT_GX  (OUT_IDX + BATCH*NPOINT*NSAMPLE)         // 17825792

// f32 -> bf16 (RNE) -> f32: match the harness's bf16-rounded np reference
__device__ __forceinline__ float rnbf(float f) {
    u32 b = __float_as_uint(f);
    b += 0x7FFFu + ((b >> 16) & 1u);
    return __uint_as_float(b & 0xFFFF0000u);
}
__device__ __forceinline__ int clampidx(int v) {
    return (v < 0) ? 0 : (v > NDATA-1 ? NDATA-1 : v);
}
// monotone x->bucket map, shared by binning and query (covering by monotonicity)
__device__ __forceinline__ int xbucket(float v) {
    int c = (int)floorf((v + 4.5f) * 28.444445f);   // 256 buckets over [-4.5, 4.5]
    return c < 0 ? 0 : (c > NB-1 ? NB-1 : c);
}

// ---- K1: per-batch bucket sort by x -> interleaved float4 {x,y,z,idbits} ----
__global__ __launch_bounds__(1024)
void bin_kernel(const float* __restrict__ xyz,
                float4* __restrict__ wp, u32* __restrict__ wst)
{
    __shared__ u32 cnt[NB];    // counts -> cursors
    __shared__ u32 sc[NB];     // scan buffer
    const int b = blockIdx.x, tid = threadIdx.x;   // 1024 threads
    const float* bx = xyz + (size_t)b * NDATA * 3;

    if (tid < NB) cnt[tid] = 0;
    __syncthreads();
    for (int p = tid; p < NDATA; p += 1024)
        atomicAdd(&cnt[xbucket(bx[p*3])], 1u);
    __syncthreads();

    // parallel inclusive scan (Hillis-Steele, 8 steps, block-uniform barriers)
    if (tid < NB) sc[tid] = cnt[tid];
    __syncthreads();
    #pragma unroll
    for (int d = 1; d < NB; d <<= 1) {
        u32 t = 0;
        if (tid < NB && tid >= d) t = sc[tid - d];
        __syncthreads();
        if (tid < NB && tid >= d) sc[tid] += t;
        __syncthreads();
    }
    if (tid < NB) {
        u32 excl = (tid == 0) ? 0u : sc[tid - 1];
        cnt[tid] = excl;                           // cursor
        wst[b*(NB+1) + tid] = excl;
        if (tid == 0) wst[b*(NB+1) + NB] = NDATA;
    }
    __syncthreads();

    for (int p = tid; p < NDATA; p += 1024) {      // scatter (bucket order arbitrary)
        float x = bx[p*3], y = bx[p*3+1], z = bx[p*3+2];
        u32 pos = atomicAdd(&cnt[xbucket(x)], 1u);
        wp[(size_t)b*NDATA + pos] = make_float4(x, y, z, __uint_as_float((u32)p));
    }
}

// ---- K2: windowed scan + verified selection + fused epilogue (R18 config) ----
__global__ __launch_bounds__(256, 8)
void grouping_kernel(const float* __restrict__ new_xyz,
                     const float* __restrict__ xyz,
                     const float* __restrict__ points,
                     const float4* __restrict__ wp, const u32* __restrict__ wst,
                     float* __restrict__ out, float T)
{
    __shared__ float cand_s[QPB][MAXCAND];   // f32 sqrt(d2)
    __shared__ int   cand_i[QPB][MAXCAND];   // point index (tie-break key)
    __shared__ int   sel[QPB][NSAMPLE];

    const int tid  = threadIdx.x;
    const int wv   = tid >> 6;
    const int lane = tid & 63;
    const int q    = blockIdx.x * QPB + wv;   // one query per wave
    const int b    = q >> 10;                 // batch

    if (lane < NSAMPLE) sel[wv][lane] = 0;    // safety net; overwritten below

    const float qx = new_xyz[q*3 + 0];
    const float qy = new_xyz[q*3 + 1];
    const float qz = new_xyz[q*3 + 2];
    const float*  bx = xyz + (size_t)b * NDATA * 3;
    const float4* cp = wp  + (size_t)b * NDATA;

    // x-window (margin 0.2005 >> any f32 rounding slop in the d2<T chain)
    const int blo = xbucket(__fsub_rn(qx, 0.2005f));
    const int bhi = xbucket(__fadd_rn(qx, 0.2005f));
    const u32 j0 = wst[b*(NB+1) + blo];
    const u32 j1 = wst[b*(NB+1) + bhi + 1];

    int n = 0;                                // wave-uniform candidate count
    for (u32 jb = j0; jb < j1; jb += 64) {    // coalesced float4 reads
        u32 j  = jb + lane;
        bool in = j < j1;
        u32 jj = in ? j : (j1 - 1);           // safe clamp (j1 >= 1 inside loop)
        float4 v = cp[jj];
        // exact np f32 semantics: no FMA, left-to-right sum
        float dx = __fsub_rn(v.x, qx);
        float dy = __fsub_rn(v.y, qy);
        float dz = __fsub_rn(v.z, qz);
        float d2 = __fadd_rn(__fadd_rn(__fmul_rn(dx,dx), __fmul_rn(dy,dy)),
                             __fmul_rn(dz,dz));
        bool cc = in && (d2 < T);             // == sqrtf(d2) < 0.2f (monotone)
        u64 m = __ballot(cc);
        if (m) {
            if (cc) {
                int below = __builtin_amdgcn_mbcnt_hi((u32)(m >> 32),
                             __builtin_amdgcn_mbcnt_lo((u32)m, 0));
                int pos = n + below;
                if (pos < MAXCAND) {
                    cand_s[wv][pos] = __fsqrt_rn(d2);   // ref sorts the f32 norm
                    cand_i[wv][pos] = (int)__float_as_uint(v.w);
                }
            }
            n += (int)__popcll(m);
        }
    }

    // ---- rare pass: argmin for empty-ball queries (R18-verified form) ----
    int mini = 0;
    if (n == 0) {
        float mind = 3.402823466e38f; int mi = 0;
        for (int k = 0; k < NDATA/64; ++k) {
            int i = (k << 6) + lane;
            float dx = __fsub_rn(bx[i*3+0], qx);
            float dy = __fsub_rn(bx[i*3+1], qy);
            float dz = __fsub_rn(bx[i*3+2], qz);
            float d2 = __fadd_rn(__fadd_rn(__fmul_rn(dx,dx), __fmul_rn(dy,dy)),
                                 __fmul_rn(dz,dz));
            if (d2 < mind) { mind = d2; mi = i; }   // strict <: lowest idx per lane
        }
        float ms = __fsqrt_rn(mind);                // np tie rule on sqrt values
        for (int off = 32; off; off >>= 1) {
            float os = __shfl_xor(ms, off);
            int   oi = __shfl_xor(mi, off);
            if (os < ms || (os == ms && oi < mi)) { ms = os; mi = oi; }
        }
        mini = mi;
    }

    __syncthreads();   // block-uniform (loops above have no barriers)

    // ---- rank-place: (dist, point-index) lex == np stable argsort ----
    const int nj = n > MAXCAND ? MAXCAND : n;
    for (int kk = lane; kk < nj; kk += 64) {
        float sk = cand_s[wv][kk];
        int   ik = cand_i[wv][kk];
        int r = 0;
        for (int mm = 0; mm < nj; ++mm) {           // broadcast LDS reads
            float sm = cand_s[wv][mm];
            int   im = cand_i[wv][mm];
            r += (int)((sm < sk) | ((sm == sk) & (im < ik)));
        }
        if (r < NSAMPLE) sel[wv][r] = clampidx(ik);
    }
    __syncthreads();
    {
        const int nsel = nj < NSAMPLE ? nj : NSAMPLE;
        if (lane >= nsel && lane < NSAMPLE) {
            int pad = (nj > 0) ? sel[wv][0] : clampidx(mini);   // sorted_idx[0]
            sel[wv][lane] = pad;
        }
    }
    __syncthreads();

    // ---- outputs: f32 stores, values pre-rounded through bf16 ----
    // idx (chunk 1)
    if (lane < NSAMPLE)
        out[OUT_IDX + (size_t)q*NSAMPLE + lane] = rnbf((float)sel[wv][lane]);

    // grouped_xyz (chunk 2)
    for (int e = lane; e < NSAMPLE*3; e += 64) {
        int sR = e / 3, c2 = e - sR*3;
        int is = sel[wv][sR];
        out[OUT_GX + (size_t)q*(NSAMPLE*3) + e] = rnbf(bx[is*3 + c2]);
    }

    // new_points (chunk 0): scalar row-major pass, 2 independent gathers in
    // flight per lane (unroll 2); each 64 B line written once
    const float* prow = points + (size_t)b * NDATA * CFEAT;
    float* onp = out + (size_t)q * (NSAMPLE*ROWF);
    #pragma unroll 2
    for (int e = lane; e < NSAMPLE*ROWF; e += 64) {
        int sR = e / ROWF;
        int c2 = e - sR*ROWF;
        int is = sel[wv][sR];
        const float* ap = (c2 < 3) ? (bx + (size_t)is*3 + c2)
                                   : (prow + (size_t)is*CFEAT + (c2-3));
        onp[e] = rnbf(*ap);
    }
}

extern "C" void kernel_launch(void* const* d_in, const int* in_sizes, int n_in,
                              void* d_out, int out_size, void* d_ws, size_t ws_size,
                              hipStream_t stream) {
    // T = smallest f32 x with sqrtf(x) >= 0.2f  =>  (d2 < T) == (sqrtf(d2) < 0.2f)
    union { u32 u; float f; } lo, hi, mid;
    lo.u = 0u; hi.f = 0.05f;
    while (hi.u - lo.u > 1u) {
        mid.u = lo.u + (hi.u - lo.u) / 2u;
        if (sqrtf(mid.f) >= 0.2f) hi.u = mid.u; else lo.u = mid.u;
    }
    float T = hi.f;

    // ws layout: wp (float4, 1 MB) | wst (u32 starts, ~8.2 KB)
    float4* wp  = (float4*)d_ws;
    u32*    wst = (u32*)(wp + (size_t)BATCH*NDATA);

    const float* nxz = (const float*)d_in[0];
    const float* xyz = (const float*)d_in[1];
    const float* pts = (const float*)d_in[2];

    bin_kernel<<<BATCH, 1024, 0, stream>>>(xyz, wp, wst);
    grouping_kernel<<<(BATCH*NPOINT)/QPB, 256, 0, stream>>>(
        nxz, xyz, pts, wp, wst, (float*)d_out, T);
}